// Round 4
// baseline (117.617 us; speedup 1.0000x reference)
//
#include <hip/hip_runtime.h>

// Problem constants (fixed by setup_inputs)
#define NB   16
#define NH   512
#define NW   512
#define RAD  4                 // window 9 -> radius 4
#define BH   8                 // output rows per wave-band
#define NBANDS (NH / BH)       // 64
#define NBLOCKS (NB * NBANDS)  // 1024 single-wave blocks
#define EPSF 1e-5f

__device__ __forceinline__ float lncc_val(float Sa, float Sb, float Saa, float Sbb, float Sab) {
    const float inv_n = 1.0f / 81.0f;
    float ma  = Sa * inv_n;
    float mb  = Sb * inv_n;
    // faithful to reference: raw local sum of squares minus mean^2, clipped at 0
    float va  = fmaxf(Saa - ma * ma, 0.0f);
    float vb  = fmaxf(Sbb - mb * mb, 0.0f);
    float cov = Sab - ma * mb;
    return cov * rsqrtf((va + EPSF) * (vb + EPSF));
}

// Add (SGN=+1) or subtract (SGN=-1) one input row's products into V.
// Lane owns 8 consecutive cols at col0 = lane*8.
template<int SGN>
__device__ __forceinline__ void accum_row(const float* __restrict__ prow,
                                          const float* __restrict__ trow,
                                          const float* __restrict__ mrow,
                                          size_t hw, int y, int col0,
                                          float (&V)[10][8])
{
    size_t off = (size_t)y * NW + col0;
    float4 p0 = *reinterpret_cast<const float4*>(prow + off);
    float4 p1 = *reinterpret_cast<const float4*>(prow + off + 4);
    float4 t0 = *reinterpret_cast<const float4*>(trow + off);
    float4 t1 = *reinterpret_cast<const float4*>(trow + off + 4);
    float4 a0 = *reinterpret_cast<const float4*>(mrow + off);        // mask ch0
    float4 a1 = *reinterpret_cast<const float4*>(mrow + off + 4);
    float4 b0 = *reinterpret_cast<const float4*>(mrow + off + hw);   // mask ch1
    float4 b1 = *reinterpret_cast<const float4*>(mrow + off + hw + 4);

    float p[8]  = {p0.x,p0.y,p0.z,p0.w, p1.x,p1.y,p1.z,p1.w};
    float t[8]  = {t0.x,t0.y,t0.z,t0.w, t1.x,t1.y,t1.z,t1.w};
    float c0[8] = {a0.x,a0.y,a0.z,a0.w, a1.x,a1.y,a1.z,a1.w};
    float c1[8] = {b0.x,b0.y,b0.z,b0.w, b1.x,b1.y,b1.z,b1.w};

    #pragma unroll
    for (int c = 0; c < 8; ++c) {
        float pv = p[c], tv = t[c];
        // argmax over 2 channels: 1 iff mask[1] > mask[0] (ties -> 0)
        float s  = (c1[c] > c0[c]) ? 1.0f : 0.0f;
        float pp = pv * pv, tt = tv * tv, pt = pv * tv;
        if (SGN > 0) {
            V[0][c] += pv; V[1][c] += tv; V[2][c] += pp; V[3][c] += tt; V[4][c] += pt;
            V[5][c] = fmaf(s, pv, V[5][c]); V[6][c] = fmaf(s, tv, V[6][c]);
            V[7][c] = fmaf(s, pp, V[7][c]); V[8][c] = fmaf(s, tt, V[8][c]);
            V[9][c] = fmaf(s, pt, V[9][c]);
        } else {
            V[0][c] -= pv; V[1][c] -= tv; V[2][c] -= pp; V[3][c] -= tt; V[4][c] -= pt;
            V[5][c] = fmaf(-s, pv, V[5][c]); V[6][c] = fmaf(-s, tv, V[6][c]);
            V[7][c] = fmaf(-s, pp, V[7][c]); V[8][c] = fmaf(-s, tt, V[8][c]);
            V[9][c] = fmaf(-s, pt, V[9][c]);
        }
    }
}

__global__ __launch_bounds__(64)
void lncc_main(const float* __restrict__ pred,
               const float* __restrict__ targ,
               const float* __restrict__ mask,
               float* __restrict__ part)
{
    const int lane = threadIdx.x;      // 64 lanes = 1 wave per block
    const int col0 = lane * 8;         // lane owns cols [col0, col0+7]
    const int b    = blockIdx.x / NBANDS;
    const int y0   = (blockIdx.x % NBANDS) * BH;

    const size_t hw   = (size_t)NH * NW;
    const float* prow = pred + (size_t)b * hw;
    const float* trow = targ + (size_t)b * hw;
    const float* mrow = mask + (size_t)b * 2 * hw;

    // running vertical 9-row sums: 10 quantities x 8 cols
    float V[10][8];
    #pragma unroll
    for (int q = 0; q < 10; ++q)
        #pragma unroll
        for (int c = 0; c < 8; ++c) V[q][c] = 0.0f;

    // warm-up rows [y0-4, y0+3] (rows <0 are zero padding)
    #pragma unroll
    for (int j = -RAD; j < RAD; ++j) {
        int y = y0 + j;
        if (y >= 0) accum_row<1>(prow, trow, mrow, hw, y, col0, V);
    }

    float sum_p = 0.0f, sum_n = 0.0f;

    for (int r = 0; r < BH; ++r) {
        int y  = y0 + r;
        int ye = y + RAD;
        if (ye < NH) accum_row<1>(prow, trow, mrow, hw, ye, col0, V);  // V spans [y-4,y+4]

        // ---- Pass A: output cols col0..col0+3 (needs prev lane's V[q][4..7]) ----
        {
            float HhA[10][4];
            #pragma unroll
            for (int q = 0; q < 10; ++q) {
                float hp0 = __shfl_up(V[q][4], 1);
                float hp1 = __shfl_up(V[q][5], 1);
                float hp2 = __shfl_up(V[q][6], 1);
                float hp3 = __shfl_up(V[q][7], 1);
                hp0 = (lane > 0) ? hp0 : 0.0f;  // image left edge is zero padding
                hp1 = (lane > 0) ? hp1 : 0.0f;
                hp2 = (lane > 0) ? hp2 : 0.0f;
                hp3 = (lane > 0) ? hp3 : 0.0f;
                float h = ((hp0 + hp1) + (hp2 + hp3))
                        + ((V[q][0] + V[q][1]) + (V[q][2] + V[q][3])) + V[q][4];
                HhA[q][0] = h;
                h += V[q][5] - hp0; HhA[q][1] = h;
                h += V[q][6] - hp1; HhA[q][2] = h;
                h += V[q][7] - hp2; HhA[q][3] = h;
            }
            #pragma unroll
            for (int c = 0; c < 4; ++c) {
                float Sa=HhA[0][c], Sb=HhA[1][c], Saa=HhA[2][c], Sbb=HhA[3][c], Sab=HhA[4][c];
                float Ma=HhA[5][c], Mb=HhA[6][c], Maa=HhA[7][c], Mbb=HhA[8][c], Mab=HhA[9][c];
                sum_n += lncc_val(Ma, Mb, Maa, Mbb, Mab);
                sum_p += lncc_val(Sa-Ma, Sb-Mb, Saa-Maa, Sbb-Mbb, Sab-Mab);
            }
        }

        // ---- Pass B: output cols col0+4..col0+7 (needs next lane's V[q][0..3]) ----
        {
            float HhB[10][4];
            #pragma unroll
            for (int q = 0; q < 10; ++q) {
                float hn0 = __shfl_down(V[q][0], 1);
                float hn1 = __shfl_down(V[q][1], 1);
                float hn2 = __shfl_down(V[q][2], 1);
                float hn3 = __shfl_down(V[q][3], 1);
                hn0 = (lane < 63) ? hn0 : 0.0f;  // image right edge is zero padding
                hn1 = (lane < 63) ? hn1 : 0.0f;
                hn2 = (lane < 63) ? hn2 : 0.0f;
                hn3 = (lane < 63) ? hn3 : 0.0f;
                float h = ((V[q][0] + V[q][1]) + (V[q][2] + V[q][3]))
                        + ((V[q][4] + V[q][5]) + (V[q][6] + V[q][7])) + hn0;
                HhB[q][0] = h;               // out col0+4
                h += hn1 - V[q][0]; HhB[q][1] = h;
                h += hn2 - V[q][1]; HhB[q][2] = h;
                h += hn3 - V[q][2]; HhB[q][3] = h;
            }
            #pragma unroll
            for (int c = 0; c < 4; ++c) {
                float Sa=HhB[0][c], Sb=HhB[1][c], Saa=HhB[2][c], Sbb=HhB[3][c], Sab=HhB[4][c];
                float Ma=HhB[5][c], Mb=HhB[6][c], Maa=HhB[7][c], Mbb=HhB[8][c], Mab=HhB[9][c];
                sum_n += lncc_val(Ma, Mb, Maa, Mbb, Mab);
                sum_p += lncc_val(Sa-Ma, Sb-Mb, Saa-Maa, Sbb-Mbb, Sab-Mab);
            }
        }

        // slide: subtract leaving row (re-load; served by L2/L3, inputs fully L3-resident)
        if (r < BH - 1) {
            int yl = y - RAD;
            if (yl >= 0) accum_row<-1>(prow, trow, mrow, hw, yl, col0, V);
        }
    }

    // wave-level reduction; one wave per block -> no LDS, no barrier
    #pragma unroll
    for (int off = 32; off > 0; off >>= 1) {
        sum_p += __shfl_down(sum_p, off, 64);
        sum_n += __shfl_down(sum_n, off, 64);
    }
    if (lane == 0) {
        part[blockIdx.x]           = sum_p;
        part[NBLOCKS + blockIdx.x] = sum_n;
    }
}

__global__ void lncc_finalize(const float* __restrict__ part, float* __restrict__ out) {
    __shared__ float w[8];
    int tid = threadIdx.x; // 256 threads
    float sp = 0.0f, sn = 0.0f;
    for (int i = tid; i < NBLOCKS; i += 256) {
        sp += part[i];
        sn += part[NBLOCKS + i];
    }
    #pragma unroll
    for (int off = 32; off > 0; off >>= 1) {
        sp += __shfl_down(sp, off, 64);
        sn += __shfl_down(sn, off, 64);
    }
    int wave = tid >> 6, lane = tid & 63;
    if (lane == 0) { w[wave] = sp; w[4 + wave] = sn; }
    __syncthreads();
    if (tid == 0) {
        double SP = (double)w[0] + (double)w[1] + (double)w[2] + (double)w[3];
        double SN = (double)w[4] + (double)w[5] + (double)w[6] + (double)w[7];
        const double npix = (double)NB * (double)NH * (double)NW;
        double mp = SP / npix;
        double mn = SN / npix;
        // LOSS_WEIGHT * (BALANCE*(1-mp) - (1-BALANCE)*(1-mn))
        out[0] = (float)(0.2 * (1.0 - mp) - 0.8 * (1.0 - mn));
    }
}

extern "C" void kernel_launch(void* const* d_in, const int* in_sizes, int n_in,
                              void* d_out, int out_size, void* d_ws, size_t ws_size,
                              hipStream_t stream) {
    const float* pred = (const float*)d_in[0];
    const float* targ = (const float*)d_in[1];
    const float* mask = (const float*)d_in[2];
    float* part = (float*)d_ws;  // 2*NBLOCKS floats, every slot written each launch

    lncc_main<<<dim3(NBLOCKS), dim3(64), 0, stream>>>(pred, targ, mask, part);
    lncc_finalize<<<dim3(1), dim3(256), 0, stream>>>(part, (float*)d_out);
}